// Round 1
// baseline (152.414 us; speedup 1.0000x reference)
//
#include <hip/hip_runtime.h>

// FeatureTransformerSlice: out[b, :] = bias + sum_k vals[b,k] * W[idx[b,k], :]
// B=16384, K=32 active features, O=512 outputs, NUM_INPUTS=45056, all fp32.
//
// One block per batch row. 128 threads; each thread owns 4 contiguous
// outputs (float4). The 32 (index, value) pairs are staged in LDS once,
// then each thread does 32 coalesced float4 gathers from the weight table
// (88 MiB -> L3-resident) and accumulates in registers.

#define B_BATCH 16384
#define K_ACT   32
#define N_OUT   512

__global__ __launch_bounds__(128) void ft_slice_kernel(
    const int*   __restrict__ idx,   // [B, K]
    const float* __restrict__ val,   // [B, K]
    const float* __restrict__ W,     // [NUM_INPUTS, N_OUT]
    const float* __restrict__ bias,  // [N_OUT]
    float*       __restrict__ out)   // [B, N_OUT]
{
    const int b = blockIdx.x;
    const int t = threadIdx.x;  // 0..127, owns outputs [4t, 4t+4)

    __shared__ int   s_idx[K_ACT];
    __shared__ float s_val[K_ACT];
    if (t < K_ACT) {
        s_idx[t] = idx[b * K_ACT + t];
        s_val[t] = val[b * K_ACT + t];
    }
    __syncthreads();

    const int col = t * 4;
    float4 acc = *reinterpret_cast<const float4*>(&bias[col]);

    // Two independent accumulators for a bit of FMA ILP; unroll so the
    // compiler can hoist/pipeline the independent global loads.
    float4 acc2 = make_float4(0.f, 0.f, 0.f, 0.f);

    #pragma unroll
    for (int k = 0; k < K_ACT; k += 2) {
        const size_t r0 = (size_t)s_idx[k]     * N_OUT;
        const size_t r1 = (size_t)s_idx[k + 1] * N_OUT;
        const float4 w0 = *reinterpret_cast<const float4*>(&W[r0 + col]);
        const float4 w1 = *reinterpret_cast<const float4*>(&W[r1 + col]);
        const float v0 = s_val[k];
        const float v1 = s_val[k + 1];
        acc.x  += v0 * w0.x;  acc.y  += v0 * w0.y;
        acc.z  += v0 * w0.z;  acc.w  += v0 * w0.w;
        acc2.x += v1 * w1.x;  acc2.y += v1 * w1.y;
        acc2.z += v1 * w1.z;  acc2.w += v1 * w1.w;
    }

    acc.x += acc2.x; acc.y += acc2.y; acc.z += acc2.z; acc.w += acc2.w;

    *reinterpret_cast<float4*>(&out[(size_t)b * N_OUT + col]) = acc;
}

extern "C" void kernel_launch(void* const* d_in, const int* in_sizes, int n_in,
                              void* d_out, int out_size, void* d_ws, size_t ws_size,
                              hipStream_t stream) {
    const int*   idx  = (const int*)  d_in[0];  // feature_indices [B,K] int32
    const float* val  = (const float*)d_in[1];  // feature_values  [B,K] f32
    const float* W    = (const float*)d_in[2];  // weight [NUM_INPUTS, N_OUT] f32
    const float* bias = (const float*)d_in[3];  // bias [N_OUT] f32
    float*       out  = (float*)d_out;          // [B, N_OUT] f32

    ft_slice_kernel<<<B_BATCH, 128, 0, stream>>>(idx, val, W, bias, out);
}